// Round 13
// baseline (53.619 us; speedup 1.0000x reference)
//
#include <hip/hip_runtime.h>

#define TPL_SIZE 16384
#define TPL_K 16
#define TPL_ND 5
#define TPL_BLK 1024
#define TPL_PTS 2                                  // points per thread
#define TPL_SPAN (TPL_BLK * TPL_PTS)               // 2048 points per block
#define TPL_BPB (TPL_SIZE / TPL_SPAN)              // 8 blocks per batch
#define TPL_NXCD 8

// R13: occupancy-doubling retry of the 1024-thread block.
// Diagnosis chain: R10 (rcp -2.3us) helped, R11/R12 (op-count / chain-length)
// were null => kernel is latency-bound at 2 waves/SIMD (128 KB LDS table
// pins 1 block/CU). A 1024-thread block gives 16 waves/CU = 4 waves/SIMD.
// R5/R6 failed because with extern-shared LDS the compiler can't see the
// 128 KB and targets 8 waves/EU (2x1024 blocks) -> 64 VGPR -> 60-90 MB
// scratch spill. __launch_bounds__ only sets a MINIMUM waves/EU;
// amdgpu_waves_per_eu(4,4) also caps the MAXIMUM at 4 -> 128-VGPR budget.
// Tells: VGPR_Count ~96-128 (not 64), WRITE_SIZE ~2 MB (no spill).
// Everything else = R10 known-good: XCD remap (batch's 8 blocks share an
// XCD L2), u16-packed table, coalesced uint4 staging, rcp-based 5x5 solve.
__global__ __launch_bounds__(TPL_BLK, 4)
__attribute__((amdgpu_waves_per_eu(4, 4)))
void tp_lds_kernel(
    const float* __restrict__ x,
    const float* __restrict__ points,
    const int*   __restrict__ edge_index,
    const float* __restrict__ dtp,
    const float* __restrict__ dist,
    const float* __restrict__ weight,
    float* __restrict__ out)
{
    extern __shared__ uint2 lds_pv[];   // [TPL_SIZE] = 128 KB

    const int tid = threadIdx.x;
    const int blk = blockIdx.x;

    // blk -> (batch, chunk): xcd = blk&7 ; 4 batches per XCD
    const int xcd   = blk & (TPL_NXCD - 1);
    const int batch = xcd * 4 + (blk >> 6);          // [0,32)
    const int chunk = (blk >> 3) & (TPL_BPB - 1);    // [0,8)

    const size_t base = (size_t)batch * TPL_SIZE + chunk * TPL_SPAN;

    // ---- issue point 0's streaming loads FIRST (hide under staging) ----
    int4   ci[4];
    float4 cw[4];
    {
        const int4*   ei = reinterpret_cast<const int4*>(edge_index + (base + tid) * TPL_K);
        const float4* dw = reinterpret_cast<const float4*>(dist      + (base + tid) * TPL_K);
        ci[0] = ei[0]; ci[1] = ei[1]; ci[2] = ei[2]; ci[3] = ei[3];
        cw[0] = dw[0]; cw[1] = dw[1]; cw[2] = dw[2]; cw[3] = dw[3];
    }

    // ---- stage + quantize the whole batch table into LDS (coalesced) ----
    {
        const float4* pb4 = reinterpret_cast<const float4*>(points + (size_t)batch * TPL_SIZE * 2);
        const float2* xb2 = reinterpret_cast<const float2*>(x + (size_t)batch * TPL_SIZE);
        uint4* lds4 = reinterpret_cast<uint4*>(lds_pv);
        #pragma unroll
        for (int k = 0; k < TPL_SIZE / (2 * TPL_BLK); ++k) {   // 8 iters
            int g = k * TPL_BLK + tid;        // pair-group index
            float4 pp = pb4[g];               // points for entries 2g, 2g+1
            float2 xv = xb2[g];               // values for entries 2g, 2g+1
            unsigned ux0 = (unsigned)(pp.x * 65536.0f);
            unsigned uy0 = (unsigned)(pp.y * 65536.0f);
            unsigned ux1 = (unsigned)(pp.z * 65536.0f);
            unsigned uy1 = (unsigned)(pp.w * 65536.0f);
            if (ux0 > 65535u) ux0 = 65535u;
            if (uy0 > 65535u) uy0 = 65535u;
            if (ux1 > 65535u) ux1 = 65535u;
            if (uy1 > 65535u) uy1 = 65535u;
            uint4 wv;
            wv.x = ux0 | (uy0 << 16);
            wv.y = __float_as_uint(xv.x);
            wv.z = ux1 | (uy1 << 16);
            wv.w = __float_as_uint(xv.y);
            lds4[g] = wv;
        }
    }
    __syncthreads();

    const float wt0 = weight[0], wt1 = weight[1], wt2 = weight[2],
                wt3 = weight[3], wt4 = weight[4];
    const float dtv = dtp[0];

    #pragma unroll
    for (int p = 0; p < TPL_PTS; ++p) {
        const int    s   = chunk * TPL_SPAN + p * TPL_BLK + tid;
        const size_t row = base + p * TPL_BLK + tid;

        // self point from LDS (same quantization as neighbors)
        uint2 se = lds_pv[s];
        unsigned sx = se.x & 0xffffu;
        unsigned sy = se.x >> 16;
        float    sv = __uint_as_float(se.y);

        int ids[TPL_K] = {ci[0].x, ci[0].y, ci[0].z, ci[0].w,
                          ci[1].x, ci[1].y, ci[1].z, ci[1].w,
                          ci[2].x, ci[2].y, ci[2].z, ci[2].w,
                          ci[3].x, ci[3].y, ci[3].z, ci[3].w};
        float wgt[TPL_K] = {cw[0].x, cw[0].y, cw[0].z, cw[0].w,
                            cw[1].x, cw[1].y, cw[1].z, cw[1].w,
                            cw[2].x, cw[2].y, cw[2].z, cw[2].w,
                            cw[3].x, cw[3].y, cw[3].z, cw[3].w};

        // gather this point's neighbors
        uint2 nb[TPL_K];
        #pragma unroll
        for (int t = 0; t < TPL_K; ++t) nb[t] = lds_pv[ids[t] & (TPL_SIZE - 1)];

        // issue next point's streaming loads now; their HBM/L2 latency
        // hides under this point's accumulate + solve (~1000+ cycles)
        if (p < TPL_PTS - 1) {
            const size_t rown = base + (p + 1) * TPL_BLK + tid;
            const int4*   ei = reinterpret_cast<const int4*>(edge_index + rown * TPL_K);
            const float4* dw = reinterpret_cast<const float4*>(dist      + rown * TPL_K);
            #pragma unroll
            for (int q = 0; q < 4; ++q) { ci[q] = ei[q]; cw[q] = dw[q]; }
        }

        float ata[15], atb[TPL_ND];
        #pragma unroll
        for (int i = 0; i < 15; ++i) ata[i] = 0.0f;
        #pragma unroll
        for (int i = 0; i < TPL_ND; ++i) atb[i] = 0.0f;

        #pragma unroll
        for (int t = 0; t < TPL_K; ++t) {
            float w = wgt[t];
            int dxi = (int)(nb[t].x & 0xffffu) - (int)sx;
            int dyi = (int)(nb[t].x >> 16)     - (int)sy;
            float dx = (float)dxi * 0x1p-16f;
            float dy = (float)dyi * 0x1p-16f;
            float nv = __uint_as_float(nb[t].y);
            float a[TPL_ND];
            a[0] = dx * w;
            a[1] = dy * w;
            a[2] = 0.5f * dx * dx * w;
            a[3] = dx * dy * w;
            a[4] = 0.5f * dy * dy * w;
            float bwv = (nv - sv) * w;
            int c = 0;
            #pragma unroll
            for (int i = 0; i < TPL_ND; ++i) {
                #pragma unroll
                for (int j = i; j < TPL_ND; ++j) ata[c++] += a[i] * a[j];
                atb[i] += a[i] * bwv;
            }
        }

        // 5x5 SPD solve, fully unrolled Gaussian elimination (regs only)
        // v_rcp_f32 pivots; reciprocals reused in back-substitution.
        float M[TPL_ND][TPL_ND], r[TPL_ND], pinv[TPL_ND];
        {
            int c = 0;
            #pragma unroll
            for (int i = 0; i < TPL_ND; ++i) {
                #pragma unroll
                for (int j = i; j < TPL_ND; ++j) { M[i][j] = ata[c]; M[j][i] = ata[c]; ++c; }
                r[i] = atb[i];
                M[i][i] += 1e-6f;
            }
        }
        #pragma unroll
        for (int i = 0; i < TPL_ND; ++i) {
            float inv = __builtin_amdgcn_rcpf(M[i][i]);
            pinv[i] = inv;
            #pragma unroll
            for (int j = i + 1; j < TPL_ND; ++j) {
                float f = M[j][i] * inv;
                #pragma unroll
                for (int cc = i + 1; cc < TPL_ND; ++cc) M[j][cc] -= f * M[i][cc];
                r[j] -= f * r[i];
            }
        }
        float sol[TPL_ND];
        #pragma unroll
        for (int i = TPL_ND - 1; i >= 0; --i) {
            float sv2 = r[i];
            #pragma unroll
            for (int cc = i + 1; cc < TPL_ND; ++cc) sv2 -= M[i][cc] * sol[cc];
            sol[i] = sv2 * pinv[i];
        }

        float du = sol[0] * wt0 + sol[1] * wt1 + sol[2] * wt2
                 + sol[3] * wt3 + sol[4] * wt4;
        out[row] = sv + dtv * du;
    }
}

extern "C" void kernel_launch(void* const* d_in, const int* in_sizes, int n_in,
                              void* d_out, int out_size, void* d_ws, size_t ws_size,
                              hipStream_t stream) {
    const float* x          = (const float*)d_in[0];
    const float* points     = (const float*)d_in[1];
    const int*   edge_index = (const int*)d_in[2];
    const float* dtp        = (const float*)d_in[3];
    const float* dist       = (const float*)d_in[4];
    const float* weight     = (const float*)d_in[5];
    float* out = (float*)d_out;

    int total = out_size;                    // B * SIZE = 524288
    int grid  = total / TPL_SPAN;            // 256 blocks (8 per batch)
    size_t lds_bytes = (size_t)TPL_SIZE * sizeof(uint2);  // 128 KB

    tp_lds_kernel<<<grid, TPL_BLK, lds_bytes, stream>>>(
        x, points, edge_index, dtp, dist, weight, out);
}

// Round 14
// 25.270 us; speedup vs baseline: 2.1219x; 2.1219x over previous
//
#include <hip/hip_runtime.h>

#define TPL_SIZE 16384
#define TPL_K 16
#define TPL_ND 5
#define TPL_BLK 512
#define TPL_PTS 4                                  // points per thread
#define TPL_SPAN (TPL_BLK * TPL_PTS)               // 2048 points per block
#define TPL_BPB (TPL_SIZE / TPL_SPAN)              // 8 blocks per batch
#define TPL_NXCD 8

typedef __attribute__((ext_vector_type(2))) float f32x2;

// R14 = R11 structure (21.0 us) + pre-packed table + global_load_lds DMA staging.
// Occupancy is pinned: 128 KB LDS table -> 1 block/CU -> 8 waves/CU
// (1024-thread blocks are dead: compiler allocates 64 VGPR regardless of
// launch_bounds/waves_per_eu attrs -> 60-110 MB scratch spill; R5/R6/R13).
// So the lever is shortening the serial staging phase: a prepass kernel
// packs {px_u16|py_u16<<16, v_f32} into d_ws once (4 MB); the main kernel
// stages its batch's 128 KB table via __builtin_amdgcn_global_load_lds
// (direct HBM/L2 -> LDS DMA, no VGPR round-trip, zero staging VALU).
// Kept: XCD remap (batch's 8 blocks share an XCD L2), depth-1 edge/dist
// prefetch pipeline, packed f32x2 accumulation, rcp-based 5x5 GE solve.
__global__ __launch_bounds__(256) void tp_pack_kernel(
    const float* __restrict__ x,
    const float* __restrict__ points,
    uint2* __restrict__ table,
    int total)
{
    int gid = blockIdx.x * blockDim.x + threadIdx.x;
    if (gid >= total) return;
    float2 p = reinterpret_cast<const float2*>(points)[gid];
    float  v = x[gid];
    unsigned ux = (unsigned)(p.x * 65536.0f);
    unsigned uy = (unsigned)(p.y * 65536.0f);
    if (ux > 65535u) ux = 65535u;
    if (uy > 65535u) uy = 65535u;
    uint2 e;
    e.x = ux | (uy << 16);
    e.y = __float_as_uint(v);
    table[gid] = e;
}

__global__ __launch_bounds__(TPL_BLK, 2) void tp_lds_kernel(
    const uint2* __restrict__ table,
    const int*   __restrict__ edge_index,
    const float* __restrict__ dtp,
    const float* __restrict__ dist,
    const float* __restrict__ weight,
    float* __restrict__ out)
{
    extern __shared__ uint2 lds_pv[];   // [TPL_SIZE] = 128 KB

    const int tid = threadIdx.x;
    const int blk = blockIdx.x;

    // blk -> (batch, chunk): xcd = blk&7 ; 4 batches per XCD
    const int xcd   = blk & (TPL_NXCD - 1);
    const int batch = xcd * 4 + (blk >> 6);          // [0,32)
    const int chunk = (blk >> 3) & (TPL_BPB - 1);    // [0,8)

    const size_t base = (size_t)batch * TPL_SIZE + chunk * TPL_SPAN;

    // ---- issue point 0's streaming loads FIRST (hide under staging DMA) ----
    int4   ci[4];
    float4 cw[4];
    {
        const int4*   ei = reinterpret_cast<const int4*>(edge_index + (base + tid) * TPL_K);
        const float4* dw = reinterpret_cast<const float4*>(dist      + (base + tid) * TPL_K);
        ci[0] = ei[0]; ci[1] = ei[1]; ci[2] = ei[2]; ci[3] = ei[3];
        cw[0] = dw[0]; cw[1] = dw[1]; cw[2] = dw[2]; cw[3] = dw[3];
    }

    // ---- stage the batch table into LDS via direct DMA (no VGPR round-trip)
    {
        const uint32_t* tb = reinterpret_cast<const uint32_t*>(table + (size_t)batch * TPL_SIZE);
        uint32_t* lraw = reinterpret_cast<uint32_t*>(lds_pv);
        #pragma unroll
        for (int k = 0; k < (TPL_SIZE * 8) / (TPL_BLK * 16); ++k) {   // 16 iters
            int i = k * TPL_BLK + tid;    // 16-byte granule index (lane-consecutive)
            __builtin_amdgcn_global_load_lds(
                (const __attribute__((address_space(1))) uint32_t*)(tb) + (size_t)i * 4,
                (__attribute__((address_space(3))) uint32_t*)(lraw) + (size_t)i * 4,
                16, 0, 0);
        }
    }
    __syncthreads();   // compiler drains vmcnt before barrier -> table ready

    const float wt0 = weight[0], wt1 = weight[1], wt2 = weight[2],
                wt3 = weight[3], wt4 = weight[4];
    const float dtv = dtp[0];

    #pragma unroll
    for (int p = 0; p < TPL_PTS; ++p) {
        const int    s   = chunk * TPL_SPAN + p * TPL_BLK + tid;
        const size_t row = base + p * TPL_BLK + tid;

        // self point from LDS (same quantization as neighbors)
        uint2 se = lds_pv[s];
        const int sx = (int)(se.x & 0xffffu);
        const int sy = (int)(se.x >> 16);
        const float sv = __uint_as_float(se.y);

        int ids[TPL_K] = {ci[0].x, ci[0].y, ci[0].z, ci[0].w,
                          ci[1].x, ci[1].y, ci[1].z, ci[1].w,
                          ci[2].x, ci[2].y, ci[2].z, ci[2].w,
                          ci[3].x, ci[3].y, ci[3].z, ci[3].w};
        float wgt[TPL_K] = {cw[0].x, cw[0].y, cw[0].z, cw[0].w,
                            cw[1].x, cw[1].y, cw[1].z, cw[1].w,
                            cw[2].x, cw[2].y, cw[2].z, cw[2].w,
                            cw[3].x, cw[3].y, cw[3].z, cw[3].w};

        // gather this point's neighbors (ids are in [0,16384) per reference)
        uint2 nb[TPL_K];
        #pragma unroll
        for (int t = 0; t < TPL_K; ++t) nb[t] = lds_pv[ids[t]];

        // issue next point's streaming loads; latency hides under accum+solve
        if (p < TPL_PTS - 1) {
            const size_t rown = base + (p + 1) * TPL_BLK + tid;
            const int4*   ei = reinterpret_cast<const int4*>(edge_index + rown * TPL_K);
            const float4* dw = reinterpret_cast<const float4*>(dist      + rown * TPL_K);
            #pragma unroll
            for (int q = 0; q < 4; ++q) { ci[q] = ei[q]; cw[q] = dw[q]; }
        }

        // ---- packed accumulation: neighbors 2tt (lo) and 2tt+1 (hi) ----
        f32x2 ata2[15], atb2[TPL_ND];
        #pragma unroll
        for (int i = 0; i < 15; ++i) ata2[i] = (f32x2)0.0f;
        #pragma unroll
        for (int i = 0; i < TPL_ND; ++i) atb2[i] = (f32x2)0.0f;

        #pragma unroll
        for (int tt = 0; tt < TPL_K / 2; ++tt) {
            const int t0 = 2 * tt, t1 = 2 * tt + 1;
            int dxi0 = (int)(nb[t0].x & 0xffffu) - sx;
            int dyi0 = (int)(nb[t0].x >> 16)     - sy;
            int dxi1 = (int)(nb[t1].x & 0xffffu) - sx;
            int dyi1 = (int)(nb[t1].x >> 16)     - sy;
            f32x2 dx = (f32x2){(float)dxi0, (float)dxi1} * 0x1p-16f;
            f32x2 dy = (f32x2){(float)dyi0, (float)dyi1} * 0x1p-16f;
            f32x2 w  = {wgt[t0], wgt[t1]};
            f32x2 nv = {__uint_as_float(nb[t0].y), __uint_as_float(nb[t1].y)};
            f32x2 hw = w * 0.5f;
            f32x2 a[TPL_ND];
            a[0] = dx * w;
            a[1] = dy * w;
            a[2] = dx * dx * hw;
            a[3] = dx * dy * w;
            a[4] = dy * dy * hw;
            f32x2 bwv = (nv - sv) * w;
            int c = 0;
            #pragma unroll
            for (int i = 0; i < TPL_ND; ++i) {
                #pragma unroll
                for (int j = i; j < TPL_ND; ++j) { ata2[c] += a[i] * a[j]; ++c; }
                atb2[i] += a[i] * bwv;
            }
        }

        // horizontal reduce lo+hi
        float ata[15], atb[TPL_ND];
        #pragma unroll
        for (int i = 0; i < 15; ++i) ata[i] = ata2[i].x + ata2[i].y;
        #pragma unroll
        for (int i = 0; i < TPL_ND; ++i) atb[i] = atb2[i].x + atb2[i].y;

        // 5x5 SPD solve, fully unrolled GE; rcp pivots reused in back-sub
        float M[TPL_ND][TPL_ND], r[TPL_ND], pinv[TPL_ND];
        {
            int c = 0;
            #pragma unroll
            for (int i = 0; i < TPL_ND; ++i) {
                #pragma unroll
                for (int j = i; j < TPL_ND; ++j) { M[i][j] = ata[c]; M[j][i] = ata[c]; ++c; }
                r[i] = atb[i];
                M[i][i] += 1e-6f;
            }
        }
        #pragma unroll
        for (int i = 0; i < TPL_ND; ++i) {
            float inv = __builtin_amdgcn_rcpf(M[i][i]);
            pinv[i] = inv;
            #pragma unroll
            for (int j = i + 1; j < TPL_ND; ++j) {
                float f = M[j][i] * inv;
                #pragma unroll
                for (int cc = i + 1; cc < TPL_ND; ++cc) M[j][cc] -= f * M[i][cc];
                r[j] -= f * r[i];
            }
        }
        float sol[TPL_ND];
        #pragma unroll
        for (int i = TPL_ND - 1; i >= 0; --i) {
            float sv2 = r[i];
            #pragma unroll
            for (int cc = i + 1; cc < TPL_ND; ++cc) sv2 -= M[i][cc] * sol[cc];
            sol[i] = sv2 * pinv[i];
        }

        float du = sol[0] * wt0 + sol[1] * wt1 + sol[2] * wt2
                 + sol[3] * wt3 + sol[4] * wt4;
        out[row] = sv + dtv * du;
    }
}

// Fallback (ws too small): R10-style in-kernel quantize staging.
__global__ __launch_bounds__(TPL_BLK, 2) void tp_lds_fallback_kernel(
    const float* __restrict__ x,
    const float* __restrict__ points,
    const int*   __restrict__ edge_index,
    const float* __restrict__ dtp,
    const float* __restrict__ dist,
    const float* __restrict__ weight,
    float* __restrict__ out)
{
    extern __shared__ uint2 lds_pv[];
    const int tid = threadIdx.x;
    const int blk = blockIdx.x;
    const int xcd   = blk & (TPL_NXCD - 1);
    const int batch = xcd * 4 + (blk >> 6);
    const int chunk = (blk >> 3) & (TPL_BPB - 1);
    const size_t base = (size_t)batch * TPL_SIZE + chunk * TPL_SPAN;

    int4 ci[4]; float4 cw[4];
    {
        const int4*   ei = reinterpret_cast<const int4*>(edge_index + (base + tid) * TPL_K);
        const float4* dw = reinterpret_cast<const float4*>(dist      + (base + tid) * TPL_K);
        ci[0] = ei[0]; ci[1] = ei[1]; ci[2] = ei[2]; ci[3] = ei[3];
        cw[0] = dw[0]; cw[1] = dw[1]; cw[2] = dw[2]; cw[3] = dw[3];
    }
    {
        const float4* pb4 = reinterpret_cast<const float4*>(points + (size_t)batch * TPL_SIZE * 2);
        const float2* xb2 = reinterpret_cast<const float2*>(x + (size_t)batch * TPL_SIZE);
        uint4* lds4 = reinterpret_cast<uint4*>(lds_pv);
        #pragma unroll
        for (int k = 0; k < TPL_SIZE / (2 * TPL_BLK); ++k) {
            int g = k * TPL_BLK + tid;
            float4 pp = pb4[g];
            float2 xv = xb2[g];
            unsigned ux0 = (unsigned)(pp.x * 65536.0f);
            unsigned uy0 = (unsigned)(pp.y * 65536.0f);
            unsigned ux1 = (unsigned)(pp.z * 65536.0f);
            unsigned uy1 = (unsigned)(pp.w * 65536.0f);
            if (ux0 > 65535u) ux0 = 65535u;
            if (uy0 > 65535u) uy0 = 65535u;
            if (ux1 > 65535u) ux1 = 65535u;
            if (uy1 > 65535u) uy1 = 65535u;
            uint4 wv;
            wv.x = ux0 | (uy0 << 16); wv.y = __float_as_uint(xv.x);
            wv.z = ux1 | (uy1 << 16); wv.w = __float_as_uint(xv.y);
            lds4[g] = wv;
        }
    }
    __syncthreads();

    const float wt0 = weight[0], wt1 = weight[1], wt2 = weight[2],
                wt3 = weight[3], wt4 = weight[4];
    const float dtv = dtp[0];

    #pragma unroll
    for (int p = 0; p < TPL_PTS; ++p) {
        const int    s   = chunk * TPL_SPAN + p * TPL_BLK + tid;
        const size_t row = base + p * TPL_BLK + tid;
        uint2 se = lds_pv[s];
        const int sx = (int)(se.x & 0xffffu);
        const int sy = (int)(se.x >> 16);
        const float sv = __uint_as_float(se.y);
        int ids[TPL_K] = {ci[0].x, ci[0].y, ci[0].z, ci[0].w,
                          ci[1].x, ci[1].y, ci[1].z, ci[1].w,
                          ci[2].x, ci[2].y, ci[2].z, ci[2].w,
                          ci[3].x, ci[3].y, ci[3].z, ci[3].w};
        float wgt[TPL_K] = {cw[0].x, cw[0].y, cw[0].z, cw[0].w,
                            cw[1].x, cw[1].y, cw[1].z, cw[1].w,
                            cw[2].x, cw[2].y, cw[2].z, cw[2].w,
                            cw[3].x, cw[3].y, cw[3].z, cw[3].w};
        uint2 nb[TPL_K];
        #pragma unroll
        for (int t = 0; t < TPL_K; ++t) nb[t] = lds_pv[ids[t]];
        if (p < TPL_PTS - 1) {
            const size_t rown = base + (p + 1) * TPL_BLK + tid;
            const int4*   ei = reinterpret_cast<const int4*>(edge_index + rown * TPL_K);
            const float4* dw = reinterpret_cast<const float4*>(dist      + rown * TPL_K);
            #pragma unroll
            for (int q = 0; q < 4; ++q) { ci[q] = ei[q]; cw[q] = dw[q]; }
        }
        float ata[15], atb[TPL_ND];
        #pragma unroll
        for (int i = 0; i < 15; ++i) ata[i] = 0.0f;
        #pragma unroll
        for (int i = 0; i < TPL_ND; ++i) atb[i] = 0.0f;
        #pragma unroll
        for (int t = 0; t < TPL_K; ++t) {
            float w = wgt[t];
            int dxi = (int)(nb[t].x & 0xffffu) - sx;
            int dyi = (int)(nb[t].x >> 16)     - sy;
            float dx = (float)dxi * 0x1p-16f;
            float dy = (float)dyi * 0x1p-16f;
            float nv = __uint_as_float(nb[t].y);
            float a[TPL_ND];
            a[0] = dx * w; a[1] = dy * w;
            a[2] = 0.5f * dx * dx * w; a[3] = dx * dy * w; a[4] = 0.5f * dy * dy * w;
            float bwv = (nv - sv) * w;
            int c = 0;
            #pragma unroll
            for (int i = 0; i < TPL_ND; ++i) {
                #pragma unroll
                for (int j = i; j < TPL_ND; ++j) ata[c++] += a[i] * a[j];
                atb[i] += a[i] * bwv;
            }
        }
        float M[TPL_ND][TPL_ND], r[TPL_ND], pinv[TPL_ND];
        {
            int c = 0;
            #pragma unroll
            for (int i = 0; i < TPL_ND; ++i) {
                #pragma unroll
                for (int j = i; j < TPL_ND; ++j) { M[i][j] = ata[c]; M[j][i] = ata[c]; ++c; }
                r[i] = atb[i];
                M[i][i] += 1e-6f;
            }
        }
        #pragma unroll
        for (int i = 0; i < TPL_ND; ++i) {
            float inv = __builtin_amdgcn_rcpf(M[i][i]);
            pinv[i] = inv;
            #pragma unroll
            for (int j = i + 1; j < TPL_ND; ++j) {
                float f = M[j][i] * inv;
                #pragma unroll
                for (int cc = i + 1; cc < TPL_ND; ++cc) M[j][cc] -= f * M[i][cc];
                r[j] -= f * r[i];
            }
        }
        float sol[TPL_ND];
        #pragma unroll
        for (int i = TPL_ND - 1; i >= 0; --i) {
            float sv2 = r[i];
            #pragma unroll
            for (int cc = i + 1; cc < TPL_ND; ++cc) sv2 -= M[i][cc] * sol[cc];
            sol[i] = sv2 * pinv[i];
        }
        float du = sol[0] * wt0 + sol[1] * wt1 + sol[2] * wt2
                 + sol[3] * wt3 + sol[4] * wt4;
        out[row] = sv + dtv * du;
    }
}

extern "C" void kernel_launch(void* const* d_in, const int* in_sizes, int n_in,
                              void* d_out, int out_size, void* d_ws, size_t ws_size,
                              hipStream_t stream) {
    const float* x          = (const float*)d_in[0];
    const float* points     = (const float*)d_in[1];
    const int*   edge_index = (const int*)d_in[2];
    const float* dtp        = (const float*)d_in[3];
    const float* dist       = (const float*)d_in[4];
    const float* weight     = (const float*)d_in[5];
    float* out = (float*)d_out;

    int total = out_size;                    // B * SIZE = 524288
    int grid  = total / TPL_SPAN;            // 256 blocks (8 per batch)
    size_t lds_bytes = (size_t)TPL_SIZE * sizeof(uint2);  // 128 KB

    size_t need = (size_t)total * sizeof(uint2);   // 4 MB packed table
    if (ws_size >= need) {
        uint2* table = (uint2*)d_ws;
        tp_pack_kernel<<<(total + 255) / 256, 256, 0, stream>>>(x, points, table, total);
        tp_lds_kernel<<<grid, TPL_BLK, lds_bytes, stream>>>(
            table, edge_index, dtp, dist, weight, out);
    } else {
        tp_lds_fallback_kernel<<<grid, TPL_BLK, lds_bytes, stream>>>(
            x, points, edge_index, dtp, dist, weight, out);
    }
}